// Round 8
// baseline (1329.291 us; speedup 1.0000x reference)
//
#include <hip/hip_runtime.h>

// ROUND 8 — fp32 OUTPUT. The harness contract ("d_out holds the reference's
// OUTPUT dtype ... else float*") dictates float* for this fp32 reference;
// rounds 0-7 wrote bf16 (misread of a hard-coded label in the test source).
// Full-FP32 VALU pipeline (R6 structure, correctness-first).
// ws (fp32): qh[3145728] kh[3145728] vh[3145728]. O overwrites qh in place.

#define NEGV (-10000.0f)
typedef __attribute__((ext_vector_type(4))) float v4f;

__global__ __launch_bounds__(256) void fill_f32(float* p, float v, int n) {
  int i = blockIdx.x * 256 + threadIdx.x;
  if (i < n) p[i] = v;
}

// ---------------------------------------------------------------- GEMM fp32
// C[64x64 tile] = A[4096x768] @ W[768x768]. 256 thr = 16x16, 4x4 per thread.
// AHEAD: A read head-major [(b*12+h)*2048+s]*64+d. CHEAD: C stored head-major.
template <bool AHEAD, bool CHEAD>
__device__ __forceinline__ void gemm_f32_core(const float* __restrict__ A,
                                              const float* __restrict__ W,
                                              float* __restrict__ C) {
  const int tid = threadIdx.x;
  const int tx = tid & 15, ty = tid >> 4;
  const int bm = blockIdx.x * 64, bn = blockIdx.y * 64;

  __shared__ __align__(16) float As[64 * 16];
  __shared__ __align__(16) float Ws[16 * 64];

  float acc[4][4];
#pragma unroll
  for (int i = 0; i < 4; i++)
#pragma unroll
    for (int j = 0; j < 4; j++) acc[i][j] = 0.f;

  for (int k0 = 0; k0 < 768; k0 += 16) {
    __syncthreads();
    {
      int row = tid >> 2, k4 = (tid & 3) << 2;   // A: 64 rows x 16 k
      int rg = bm + row, c = k0 + k4;
      size_t aoff;
      if (AHEAD)
        aoff = ((size_t)((rg >> 11) * 12 + (c >> 6)) * 2048 + (rg & 2047)) * 64
               + (c & 63);
      else
        aoff = (size_t)rg * 768 + c;
      *(float4*)&As[row * 16 + k4] = *(const float4*)(A + aoff);
      int kr = tid >> 4, n4 = (tid & 15) << 2;   // W: 16 k-rows x 64 n
      *(float4*)&Ws[kr * 64 + n4] =
          *(const float4*)(W + (size_t)(k0 + kr) * 768 + bn + n4);
    }
    __syncthreads();
#pragma unroll 4
    for (int kk = 0; kk < 16; kk++) {
      float a[4], w[4];
#pragma unroll
      for (int i = 0; i < 4; i++) a[i] = As[(ty * 4 + i) * 16 + kk];
#pragma unroll
      for (int j = 0; j < 4; j++) w[j] = Ws[kk * 64 + tx * 4 + j];
#pragma unroll
      for (int i = 0; i < 4; i++)
#pragma unroll
        for (int j = 0; j < 4; j++) acc[i][j] += a[i] * w[j];
    }
  }

#pragma unroll
  for (int i = 0; i < 4; i++) {
    int row = bm + ty * 4 + i;
#pragma unroll
    for (int j = 0; j < 4; j++) {
      int col = bn + tx * 4 + j;
      size_t off;
      if (CHEAD)
        off = ((size_t)((row >> 11) * 12 + (col >> 6)) * 2048 + (row & 2047))
              * 64 + (col & 63);
      else
        off = (size_t)row * 768 + col;
      C[off] = acc[i][j];
    }
  }
}

__global__ __launch_bounds__(256) void gemm_qkv_f32(
    const float* __restrict__ xq, const float* __restrict__ xk,
    const float* __restrict__ xv, const float* __restrict__ Wq,
    const float* __restrict__ Wk, const float* __restrict__ Wv,
    float* __restrict__ qh, float* __restrict__ kh, float* __restrict__ vh) {
  const float* A; const float* W; float* C;
  switch (blockIdx.z) {
    case 0: A = xq; W = Wq; C = qh; break;
    case 1: A = xk; W = Wk; C = kh; break;
    default: A = xv; W = Wv; C = vh; break;
  }
  gemm_f32_core<false, true>(A, W, C);
}

__global__ __launch_bounds__(256) void gemm_o_f32(
    const float* __restrict__ oat, const float* __restrict__ Wo,
    float* __restrict__ out) {
  gemm_f32_core<true, false>(oat, Wo, out);
}

// ------------------------------------------------------- attention fp32 VALU
// grid (32, 24). thread = (ql = tid>>2 in [0,64), part = tid&3).
// part owns keys part*16+j of each 64-key tile and output dims part*16..+15.
__global__ __launch_bounds__(256) void attn_f32(
    const float* __restrict__ qh, const float* __restrict__ kh,
    const float* __restrict__ vh, const int* __restrict__ attn_mask,
    const int* __restrict__ mask_future, float* __restrict__ o) {
  const int S = 2048, HD = 64, NH = 12;
  const int qt = blockIdx.x, bh = blockIdx.y;
  const int b = bh / NH, h = bh % NH;
  const int tid = threadIdx.x;
  const int lane = tid & 63;
  const int ql = tid >> 2, part = tid & 3;

  __shared__ __align__(16) float Qs[64 * 64];
  __shared__ __align__(16) float Ks[64 * 64];
  __shared__ __align__(16) float Vs[64 * 64];
  __shared__ int Ms[64];

  const size_t head_off = (size_t)(b * NH + h) * S * HD;
  const float* Qb = qh + head_off + (size_t)qt * 64 * HD;
  const float* Kb = kh + head_off;
  const float* Vb = vh + head_off;

#pragma unroll
  for (int vv = 0; vv < 4; vv++) {
    int e = vv * 256 + tid;
    *(float4*)&Qs[e * 4] = *(const float4*)&Qb[e * 4];
  }

  const int mf = mask_future[0];
  const int qabs = qt * 64 + ql;

  float m_i = -1e30f, l_i = 0.f;
  v4f O4[4];
#pragma unroll
  for (int dd = 0; dd < 4; dd++) O4[dd] = (v4f){0.f, 0.f, 0.f, 0.f};

  const v4f* Qs4 = (const v4f*)Qs;
  const v4f* Ks4 = (const v4f*)Ks;
  const v4f* Vs4 = (const v4f*)Vs;

  for (int kt = 0; kt < S / 64; kt++) {
#pragma unroll
    for (int vv = 0; vv < 4; vv++) {
      int e = vv * 256 + tid;
      *(float4*)&Ks[e * 4] = *(const float4*)&Kb[(size_t)kt * 64 * HD + e * 4];
      *(float4*)&Vs[e * 4] = *(const float4*)&Vb[(size_t)kt * 64 * HD + e * 4];
    }
    if (tid < 64) Ms[tid] = attn_mask[b * S + kt * 64 + tid];
    __syncthreads();

    float s[16];
#pragma unroll
    for (int j = 0; j < 16; j++) s[j] = 0.f;
    for (int dc = 0; dc < 16; dc++) {
      v4f qv = Qs4[ql * 16 + dc];
#pragma unroll
      for (int j = 0; j < 16; j++) {
        v4f kv = Ks4[(part * 16 + j) * 16 + dc];
        s[j] += qv[0] * kv[0] + qv[1] * kv[1] + qv[2] * kv[2] + qv[3] * kv[3];
      }
    }

    // scale + causal (additive NEG) + padding (replace NEG) — exact ref
#pragma unroll
    for (int j = 0; j < 16; j++) {
      int kl = part * 16 + j;
      int key = kt * 64 + kl;
      float v = s[j] * 0.125f;
      v += (mf && (key > qabs)) ? NEGV : 0.f;
      v = (Ms[kl] == 0) ? NEGV : v;
      s[j] = v;
    }

    // online softmax; row = 4 adjacent lanes
    float mx = s[0];
#pragma unroll
    for (int j = 1; j < 16; j++) mx = fmaxf(mx, s[j]);
    mx = fmaxf(mx, __shfl_xor(mx, 1));
    mx = fmaxf(mx, __shfl_xor(mx, 2));
    float mnew = fmaxf(m_i, mx);
    float alpha = __expf(m_i - mnew);
    m_i = mnew;
    float rs = 0.f;
#pragma unroll
    for (int j = 0; j < 16; j++) {
      float p = __expf(s[j] - mnew);
      s[j] = p;
      rs += p;
    }
    rs += __shfl_xor(rs, 1);
    rs += __shfl_xor(rs, 2);
    l_i = l_i * alpha + rs;
#pragma unroll
    for (int dd = 0; dd < 4; dd++) O4[dd] *= alpha;

    // O += P @ V (P via shuffle from the other 3 parts)
#pragma unroll
    for (int sp = 0; sp < 4; sp++) {
      int src = (lane & ~3) | sp;
#pragma unroll
      for (int j = 0; j < 16; j++) {
        float p = __shfl(s[j], src);
        int kl = sp * 16 + j;
#pragma unroll
        for (int dd = 0; dd < 4; dd++) O4[dd] += p * Vs4[kl * 16 + part * 4 + dd];
      }
    }
    __syncthreads();
  }

  float inv = 1.f / l_i;
  size_t base = head_off + (size_t)qabs * HD + part * 16;
#pragma unroll
  for (int dd = 0; dd < 4; dd++)
#pragma unroll
    for (int c = 0; c < 4; c++)
      o[base + dd * 4 + c] = O4[dd][c] * inv;
}

// ---------------------------------------------------------------- launch
extern "C" void kernel_launch(void* const* d_in, const int* in_sizes, int n_in,
                              void* d_out, int out_size, void* d_ws, size_t ws_size,
                              hipStream_t stream) {
  float* out = (float*)d_out;
  const int fill_grid = (out_size + 255) / 256;

  // contract sentinels (none fired in R6/R7; kept as guards)
  const int expect[9] = {3145728, 3145728, 3145728, 4096,
                         589824, 589824, 589824, 589824, 1};
  bool ok = (n_in == 9) && (out_size == 3145728);
  if (ok)
    for (int i = 0; i < 9; i++) ok = ok && (in_sizes[i] == expect[i]);
  if (!ok) {  // sentinel: 100.0 -> contract not what we assume
    fill_f32<<<fill_grid, 256, 0, stream>>>(out, 100.0f, out_size);
    return;
  }
  if (ws_size < (size_t)3 * 3145728 * 4) {  // sentinel: 200.0
    fill_f32<<<fill_grid, 256, 0, stream>>>(out, 200.0f, out_size);
    return;
  }

  const float* q  = (const float*)d_in[0];
  const float* k  = (const float*)d_in[1];
  const float* v  = (const float*)d_in[2];
  const int* amask = (const int*)d_in[3];
  const float* Wq = (const float*)d_in[4];
  const float* Wk = (const float*)d_in[5];
  const float* Wv = (const float*)d_in[6];
  const float* Wo = (const float*)d_in[7];
  const int* mf  = (const int*)d_in[8];

  float* ws = (float*)d_ws;
  float* qh = ws;                  // O overwrites qh after attention
  float* kh = qh + 3145728;
  float* vh = kh + 3145728;

  gemm_qkv_f32<<<dim3(64, 12, 3), 256, 0, stream>>>(q, k, v, Wq, Wk, Wv,
                                                    qh, kh, vh);
  attn_f32<<<dim3(32, 24), 256, 0, stream>>>(qh, kh, vh, amask, mf, qh);
  gemm_o_f32<<<dim3(64, 12), 256, 0, stream>>>(qh, Wo, out);
}

// Round 9
// 324.273 us; speedup vs baseline: 4.0993x; 4.0993x over previous
//
#include <hip/hip_runtime.h>

// ROUND 9 — bf16 MFMA pipeline, fp32 I/O (contract proven in R8).
// gemm_qkv: X[4096x768]f32 @ W[768x768]f32 -> qh/kh/vh bf16 head-major.
// attn:     MFMA flash attention (fp32 softmax), O -> bf16 in-place over qh.
// gemm_o:   O bf16 head-major @ Wo f32 -> d_out f32 row-major.
// ws (bf16): qh[3145728] kh[3145728] vh[3145728] = 18.9 MB.

#define NEGV (-10000.0f)

typedef __attribute__((ext_vector_type(8))) short v8s;
typedef __attribute__((ext_vector_type(4))) float v4f;
typedef __attribute__((ext_vector_type(8))) unsigned short v8u;

__device__ __forceinline__ unsigned short f2bf(float f) {
  unsigned int u = __float_as_uint(f);
  u += 0x7FFFu + ((u >> 16) & 1u);   // RNE
  return (unsigned short)(u >> 16);
}

// ---------------------------------------------------------------- GEMM core
// 128x128 tile, 4 waves 2x2, 16x16x32 bf16 MFMA, BK=32.
// ABF16HEAD: A is bf16 head-major [(b*12+h)*2048+s]*64+d ; else fp32 row-major.
// CF32ROW:   C is fp32 row-major (d_out) ; else bf16 head-major.
template <bool ABF16HEAD, bool CF32ROW>
__device__ __forceinline__ void gemm_core(const void* __restrict__ A,
                                          const float* __restrict__ W,
                                          void* __restrict__ C) {
  const int tid = threadIdx.x;
  const int wave = tid >> 6, lane = tid & 63;
  const int quad = lane >> 4, l16 = lane & 15;
  const int wm = wave >> 1, wn = wave & 1;
  const int bm = blockIdx.x * 128, bn = blockIdx.y * 128;

  __shared__ __align__(16) unsigned short As[128 * 32];
  __shared__ __align__(16) unsigned short Bs[128 * 32];

  v4f acc[4][4];
#pragma unroll
  for (int i = 0; i < 4; i++)
#pragma unroll
    for (int j = 0; j < 4; j++) acc[i][j] = (v4f){0.f, 0.f, 0.f, 0.f};

  for (int kt = 0; kt < 24; kt++) {
    __syncthreads();
    // ---- A staging: As[r][k] = A[bm+r][kt*32+k]
#pragma unroll
    for (int p = 0; p < 2; p++) {
      int idx = p * 256 + tid;
      int r = idx >> 2, c0 = (idx & 3) << 3;
      int rg = bm + r, c = kt * 32 + c0;
      if (ABF16HEAD) {
        size_t aoff = ((size_t)((rg >> 11) * 12 + (c >> 6)) * 2048 +
                       (rg & 2047)) * 64 + (c & 63);
        *(uint4*)&As[r * 32 + c0] =
            *(const uint4*)((const unsigned short*)A + aoff);
      } else {
        const float* Af = (const float*)A;
        size_t aoff = (size_t)rg * 768 + c;
        float4 x0 = *(const float4*)(Af + aoff);
        float4 x1 = *(const float4*)(Af + aoff + 4);
        v8u tmp;
        tmp[0] = f2bf(x0.x); tmp[1] = f2bf(x0.y);
        tmp[2] = f2bf(x0.z); tmp[3] = f2bf(x0.w);
        tmp[4] = f2bf(x1.x); tmp[5] = f2bf(x1.y);
        tmp[6] = f2bf(x1.z); tmp[7] = f2bf(x1.w);
        *(uint4*)&As[r * 32 + c0] = *(uint4*)&tmp;
      }
    }
    // ---- B staging: Bs[n][k] = W[kt*32+k][bn+n] (coalesced fp32 row reads)
#pragma unroll
    for (int p = 0; p < 2; p++) {
      int idx = p * 256 + tid;
      int kk = idx >> 4, n0 = (idx & 15) << 3;
      size_t woff = (size_t)(kt * 32 + kk) * 768 + bn + n0;
      float4 x0 = *(const float4*)(W + woff);
      float4 x1 = *(const float4*)(W + woff + 4);
      unsigned short vals[8];
      vals[0] = f2bf(x0.x); vals[1] = f2bf(x0.y);
      vals[2] = f2bf(x0.z); vals[3] = f2bf(x0.w);
      vals[4] = f2bf(x1.x); vals[5] = f2bf(x1.y);
      vals[6] = f2bf(x1.z); vals[7] = f2bf(x1.w);
#pragma unroll
      for (int j = 0; j < 8; j++) Bs[(n0 + j) * 32 + kk] = vals[j];
    }
    __syncthreads();

    v8s aF[4], bF[4];
#pragma unroll
    for (int mt = 0; mt < 4; mt++)
      aF[mt] = *(const v8s*)&As[(wm * 64 + mt * 16 + l16) * 32 + quad * 8];
#pragma unroll
    for (int nt = 0; nt < 4; nt++)
      bF[nt] = *(const v8s*)&Bs[(wn * 64 + nt * 16 + l16) * 32 + quad * 8];
#pragma unroll
    for (int mt = 0; mt < 4; mt++)
#pragma unroll
      for (int nt = 0; nt < 4; nt++)
        acc[mt][nt] = __builtin_amdgcn_mfma_f32_16x16x32_bf16(
            aF[mt], bF[nt], acc[mt][nt], 0, 0, 0);
  }

  // epilogue: C/D layout row(m) = quad*4+i, col(n) = l16
#pragma unroll
  for (int mt = 0; mt < 4; mt++) {
#pragma unroll
    for (int i = 0; i < 4; i++) {
      int row = bm + wm * 64 + mt * 16 + quad * 4 + i;
#pragma unroll
      for (int nt = 0; nt < 4; nt++) {
        int col = bn + wn * 64 + nt * 16 + l16;
        if (CF32ROW) {
          ((float*)C)[(size_t)row * 768 + col] = acc[mt][nt][i];
        } else {
          size_t off = ((size_t)((row >> 11) * 12 + (col >> 6)) * 2048 +
                        (row & 2047)) * 64 + (col & 63);
          ((unsigned short*)C)[off] = f2bf(acc[mt][nt][i]);
        }
      }
    }
  }
}

__global__ __launch_bounds__(256) void gemm_qkv(
    const float* __restrict__ xq, const float* __restrict__ xk,
    const float* __restrict__ xv, const float* __restrict__ Wq,
    const float* __restrict__ Wk, const float* __restrict__ Wv,
    unsigned short* __restrict__ qh, unsigned short* __restrict__ kh,
    unsigned short* __restrict__ vh) {
  const float* A; const float* W; unsigned short* C;
  switch (blockIdx.z) {
    case 0: A = xq; W = Wq; C = qh; break;
    case 1: A = xk; W = Wk; C = kh; break;
    default: A = xv; W = Wv; C = vh; break;
  }
  gemm_core<false, false>((const void*)A, W, (void*)C);
}

__global__ __launch_bounds__(256) void gemm_o(
    const unsigned short* __restrict__ oat, const float* __restrict__ Wo,
    float* __restrict__ out) {
  gemm_core<true, true>((const void*)oat, Wo, (void*)out);
}

// ---------------------------------------------------------------- attention
// grid (32, 24): x = q-tile (64 rows), y = b*12+h. 4 waves x 16 q-rows.
// MFMA QK^T and PV; fp32 online softmax; exact additive-NEG semantics.
__global__ __launch_bounds__(256) void attn_kernel(
    const unsigned short* __restrict__ qh, const unsigned short* __restrict__ kh,
    const unsigned short* __restrict__ vh, const int* __restrict__ attn_mask,
    const int* __restrict__ mask_future, unsigned short* __restrict__ o) {
  const int S = 2048, HD = 64, NH = 12;
  const int qt = blockIdx.x;
  const int bh = blockIdx.y;
  const int b = bh / NH, h = bh % NH;
  const int tid = threadIdx.x;
  const int wave = tid >> 6, lane = tid & 63;
  const int quad = lane >> 4, l16 = lane & 15;

  __shared__ __align__(16) unsigned short Ks[64 * 72];    // [key][k], pad 72
  __shared__ __align__(16) unsigned short Vt[64 * 72];    // [d][s-swizzled]
  __shared__ __align__(16) unsigned short Ps[4][16 * 72]; // per-wave P tile
  __shared__ int Ms[64];

  const size_t head_off = (size_t)(b * NH + h) * S * HD;
  const unsigned short* Kb = kh + head_off;
  const unsigned short* Vb = vh + head_off;

  const int mf = mask_future[0];

  // Q A-frags (m = l16, k = quad*8 + j), register-resident for whole kernel
  const int qrowA = qt * 64 + wave * 16 + l16;
  v8s aQ[2];
  {
    const unsigned short* qp = qh + head_off + (size_t)qrowA * HD + quad * 8;
    aQ[0] = *(const v8s*)(qp);
    aQ[1] = *(const v8s*)(qp + 32);
  }
  const int qbase = qt * 64 + wave * 16 + quad * 4;  // + i -> C-layout row

  float m_i[4], l_i[4];
  v4f accO[4];  // accO[dt][i] : rows i (C layout), d = dt*16 + l16
#pragma unroll
  for (int i = 0; i < 4; i++) { m_i[i] = -1e30f; l_i[i] = 0.f; }
#pragma unroll
  for (int dt = 0; dt < 4; dt++) accO[dt] = (v4f){0.f, 0.f, 0.f, 0.f};

  for (int kt = 0; kt < S / 64; kt++) {
    __syncthreads();
    {
      const uint4* srck = (const uint4*)(Kb + (size_t)kt * 64 * HD);
      const uint4* srcv = (const uint4*)(Vb + (size_t)kt * 64 * HD);
#pragma unroll
      for (int p = 0; p < 2; p++) {
        int idx = p * 256 + tid;
        int r = idx >> 3;              // source row s
        int c0 = (idx & 7) << 3;       // source col d0
        *(uint4*)&Ks[r * 72 + c0] = srck[idx];
        v8u vv;
        *(uint4*)&vv = srcv[idx];
        int shift = (idx & 7) << 3;    // 8*(d>>3)
#pragma unroll
        for (int i = 0; i < 8; i++) {
          int d = c0 + i;
          int scol = (r + shift) & 63; // diagonal swizzle
          Vt[d * 72 + scol] = vv[i];
        }
      }
      if (tid < 64) Ms[tid] = attn_mask[b * S + kt * 64 + tid];
    }
    __syncthreads();

    // S = Q K^T
    v4f sc[4];
#pragma unroll
    for (int nt = 0; nt < 4; nt++) {
      const unsigned short* kp = &Ks[(nt * 16 + l16) * 72 + quad * 8];
      v8s b0 = *(const v8s*)kp;
      v8s b1 = *(const v8s*)(kp + 32);
      v4f z = (v4f){0.f, 0.f, 0.f, 0.f};
      z = __builtin_amdgcn_mfma_f32_16x16x32_bf16(aQ[0], b0, z, 0, 0, 0);
      z = __builtin_amdgcn_mfma_f32_16x16x32_bf16(aQ[1], b1, z, 0, 0, 0);
      sc[nt] = z;
    }

    // scale + causal(add NEG) + padding(replace NEG) — exact ref semantics
#pragma unroll
    for (int nt = 0; nt < 4; nt++) {
      int key = kt * 64 + nt * 16 + l16;
      bool pad = (Ms[nt * 16 + l16] == 0);
#pragma unroll
      for (int i = 0; i < 4; i++) {
        float v = sc[nt][i] * 0.125f;
        v += (mf && (key > qbase + i)) ? NEGV : 0.f;
        v = pad ? NEGV : v;
        sc[nt][i] = v;
      }
    }

    // online softmax (row spread across the 16 lanes of each quad)
#pragma unroll
    for (int i = 0; i < 4; i++) {
      float mx = fmaxf(fmaxf(sc[0][i], sc[1][i]), fmaxf(sc[2][i], sc[3][i]));
      mx = fmaxf(mx, __shfl_xor(mx, 1));
      mx = fmaxf(mx, __shfl_xor(mx, 2));
      mx = fmaxf(mx, __shfl_xor(mx, 4));
      mx = fmaxf(mx, __shfl_xor(mx, 8));
      float mnew = fmaxf(m_i[i], mx);
      float alpha = __expf(m_i[i] - mnew);
      m_i[i] = mnew;
      float rs = 0.f;
#pragma unroll
      for (int nt = 0; nt < 4; nt++) {
        float p = __expf(sc[nt][i] - mnew);
        sc[nt][i] = p;
        rs += p;
      }
      rs += __shfl_xor(rs, 1);
      rs += __shfl_xor(rs, 2);
      rs += __shfl_xor(rs, 4);
      rs += __shfl_xor(rs, 8);
      l_i[i] = l_i[i] * alpha + rs;
#pragma unroll
      for (int dt = 0; dt < 4; dt++) accO[dt][i] *= alpha;
    }

    // P: C-layout regs -> per-wave LDS -> A-layout frags (m120 pattern)
#pragma unroll
    for (int nt = 0; nt < 4; nt++)
#pragma unroll
      for (int i = 0; i < 4; i++)
        Ps[wave][(quad * 4 + i) * 72 + nt * 16 + l16] = f2bf(sc[nt][i]);

#pragma unroll
    for (int ks = 0; ks < 2; ks++) {
      v8s aP = *(const v8s*)&Ps[wave][l16 * 72 + ks * 32 + quad * 8];
#pragma unroll
      for (int dt = 0; dt < 4; dt++) {
        int d = dt * 16 + l16;
        int scol = ((ks * 32 + quad * 8) + ((d >> 3) << 3)) & 63;
        v8s bV = *(const v8s*)&Vt[d * 72 + scol];
        accO[dt] = __builtin_amdgcn_mfma_f32_16x16x32_bf16(aP, bV, accO[dt], 0, 0, 0);
      }
    }
  }

  // normalize + store O bf16 head-major over own Q region (in place)
#pragma unroll
  for (int i = 0; i < 4; i++) {
    float inv = 1.f / l_i[i];
    int qr = qbase + i;
    size_t base = head_off + (size_t)qr * HD;
#pragma unroll
    for (int dt = 0; dt < 4; dt++)
      o[base + dt * 16 + l16] = f2bf(accO[dt][i] * inv);
  }
}

// ---------------------------------------------------------------- launch
extern "C" void kernel_launch(void* const* d_in, const int* in_sizes, int n_in,
                              void* d_out, int out_size, void* d_ws, size_t ws_size,
                              hipStream_t stream) {
  const float* q  = (const float*)d_in[0];
  const float* k  = (const float*)d_in[1];
  const float* v  = (const float*)d_in[2];
  const int* amask = (const int*)d_in[3];
  const float* Wq = (const float*)d_in[4];
  const float* Wk = (const float*)d_in[5];
  const float* Wv = (const float*)d_in[6];
  const float* Wo = (const float*)d_in[7];
  const int* mf  = (const int*)d_in[8];
  float* out = (float*)d_out;

  unsigned short* ws = (unsigned short*)d_ws;
  unsigned short* qh = ws;                  // O overwrites qh after attention
  unsigned short* kh = qh + 3145728;
  unsigned short* vh = kh + 3145728;

  gemm_qkv<<<dim3(32, 6, 3), 256, 0, stream>>>(q, k, v, Wq, Wk, Wv, qh, kh, vh);
  attn_kernel<<<dim3(32, 24), 256, 0, stream>>>(qh, kh, vh, amask, mf, qh);
  gemm_o<<<dim3(32, 6), 256, 0, stream>>>(qh, Wo, out);
}

// Round 10
// 246.716 us; speedup vs baseline: 5.3879x; 1.3144x over previous
//
#include <hip/hip_runtime.h>

// ROUND 10 — perf: (1) pre-transposed bf16 weights -> contiguous ds_write_b128
// B staging in both GEMMs; (2) exact causal tile-skipping in attention with
// fully-padded-row fallback.
// ws (bf16): qh[3145728] kh[3145728] vh[3145728] wt[4*589824] = 23.6 MB.
// O overwrites qh in place after attention.

#define NEGV (-10000.0f)

typedef __attribute__((ext_vector_type(8))) short v8s;
typedef __attribute__((ext_vector_type(4))) float v4f;
typedef __attribute__((ext_vector_type(8))) unsigned short v8u;

__device__ __forceinline__ unsigned short f2bf(float f) {
  unsigned int u = __float_as_uint(f);
  u += 0x7FFFu + ((u >> 16) & 1u);   // RNE
  return (unsigned short)(u >> 16);
}

// ---------------------------------------------------------------- W transpose
// W fp32 [k][n] -> Wt bf16 [n][k]; 4 matrices via z.
__global__ __launch_bounds__(256) void transpose_w(
    const float* __restrict__ w0, const float* __restrict__ w1,
    const float* __restrict__ w2, const float* __restrict__ w3,
    unsigned short* __restrict__ t0, unsigned short* __restrict__ t1,
    unsigned short* __restrict__ t2, unsigned short* __restrict__ t3) {
  const float* w; unsigned short* t;
  switch (blockIdx.z) {
    case 0: w = w0; t = t0; break;
    case 1: w = w1; t = t1; break;
    case 2: w = w2; t = t2; break;
    default: w = w3; t = t3; break;
  }
  __shared__ unsigned short tile[32][33];
  const int tx = threadIdx.x & 31, ty = threadIdx.x >> 5;
  const int x0 = blockIdx.x * 32, y0 = blockIdx.y * 32;
#pragma unroll
  for (int j = 0; j < 4; j++)
    tile[ty + j * 8][tx] = f2bf(w[(size_t)(y0 + ty + j * 8) * 768 + x0 + tx]);
  __syncthreads();
#pragma unroll
  for (int j = 0; j < 4; j++)
    t[(size_t)(x0 + ty + j * 8) * 768 + y0 + tx] = tile[tx][ty + j * 8];
}

// ---------------------------------------------------------------- GEMM core
// 128x128 tile, 4 waves 2x2, 16x16x32 bf16 MFMA, BK=32.
// A: fp32 row-major (converted in regs) or bf16 head-major.
// B: bf16 Wt[n][k] -> contiguous uint4 + ds_write_b128.
// C: bf16 head-major or fp32 row-major (d_out).
template <bool ABF16HEAD, bool CF32ROW>
__device__ __forceinline__ void gemm_core(const void* __restrict__ A,
                                          const unsigned short* __restrict__ Wt,
                                          void* __restrict__ C) {
  const int tid = threadIdx.x;
  const int wave = tid >> 6, lane = tid & 63;
  const int quad = lane >> 4, l16 = lane & 15;
  const int wm = wave >> 1, wn = wave & 1;
  const int bm = blockIdx.x * 128, bn = blockIdx.y * 128;

  __shared__ __align__(16) unsigned short As[128 * 32];
  __shared__ __align__(16) unsigned short Bs[128 * 32];

  v4f acc[4][4];
#pragma unroll
  for (int i = 0; i < 4; i++)
#pragma unroll
    for (int j = 0; j < 4; j++) acc[i][j] = (v4f){0.f, 0.f, 0.f, 0.f};

  for (int kt = 0; kt < 24; kt++) {
    __syncthreads();
#pragma unroll
    for (int p = 0; p < 2; p++) {
      int idx = p * 256 + tid;
      int r = idx >> 2, c0 = (idx & 3) << 3;
      // ---- A staging: As[r][k] = A[bm+r][kt*32+k]
      int rg = bm + r, c = kt * 32 + c0;
      if (ABF16HEAD) {
        size_t aoff = ((size_t)((rg >> 11) * 12 + (c >> 6)) * 2048 +
                       (rg & 2047)) * 64 + (c & 63);
        *(uint4*)&As[r * 32 + c0] =
            *(const uint4*)((const unsigned short*)A + aoff);
      } else {
        const float* Af = (const float*)A;
        size_t aoff = (size_t)rg * 768 + c;
        float4 x0 = *(const float4*)(Af + aoff);
        float4 x1 = *(const float4*)(Af + aoff + 4);
        v8u tmp;
        tmp[0] = f2bf(x0.x); tmp[1] = f2bf(x0.y);
        tmp[2] = f2bf(x0.z); tmp[3] = f2bf(x0.w);
        tmp[4] = f2bf(x1.x); tmp[5] = f2bf(x1.y);
        tmp[6] = f2bf(x1.z); tmp[7] = f2bf(x1.w);
        *(uint4*)&As[r * 32 + c0] = *(uint4*)&tmp;
      }
      // ---- B staging: Bs[n][k] = Wt[bn+n][kt*32+k] (contiguous 16B)
      *(uint4*)&Bs[r * 32 + c0] =
          *(const uint4*)&Wt[(size_t)(bn + r) * 768 + c];
    }
    __syncthreads();

    v8s aF[4], bF[4];
#pragma unroll
    for (int mt = 0; mt < 4; mt++)
      aF[mt] = *(const v8s*)&As[(wm * 64 + mt * 16 + l16) * 32 + quad * 8];
#pragma unroll
    for (int nt = 0; nt < 4; nt++)
      bF[nt] = *(const v8s*)&Bs[(wn * 64 + nt * 16 + l16) * 32 + quad * 8];
#pragma unroll
    for (int mt = 0; mt < 4; mt++)
#pragma unroll
      for (int nt = 0; nt < 4; nt++)
        acc[mt][nt] = __builtin_amdgcn_mfma_f32_16x16x32_bf16(
            aF[mt], bF[nt], acc[mt][nt], 0, 0, 0);
  }

  // epilogue: C/D layout row(m) = quad*4+i, col(n) = l16
#pragma unroll
  for (int mt = 0; mt < 4; mt++) {
#pragma unroll
    for (int i = 0; i < 4; i++) {
      int row = bm + wm * 64 + mt * 16 + quad * 4 + i;
#pragma unroll
      for (int nt = 0; nt < 4; nt++) {
        int col = bn + wn * 64 + nt * 16 + l16;
        if (CF32ROW) {
          ((float*)C)[(size_t)row * 768 + col] = acc[mt][nt][i];
        } else {
          size_t off = ((size_t)((row >> 11) * 12 + (col >> 6)) * 2048 +
                        (row & 2047)) * 64 + (col & 63);
          ((unsigned short*)C)[off] = f2bf(acc[mt][nt][i]);
        }
      }
    }
  }
}

__global__ __launch_bounds__(256) void gemm_qkv(
    const float* __restrict__ xq, const float* __restrict__ xk,
    const float* __restrict__ xv, const unsigned short* __restrict__ wqt,
    const unsigned short* __restrict__ wkt, const unsigned short* __restrict__ wvt,
    unsigned short* __restrict__ qh, unsigned short* __restrict__ kh,
    unsigned short* __restrict__ vh) {
  const float* A; const unsigned short* Wt; unsigned short* C;
  switch (blockIdx.z) {
    case 0: A = xq; Wt = wqt; C = qh; break;
    case 1: A = xk; Wt = wkt; C = kh; break;
    default: A = xv; Wt = wvt; C = vh; break;
  }
  gemm_core<false, false>((const void*)A, Wt, (void*)C);
}

__global__ __launch_bounds__(256) void gemm_o(
    const unsigned short* __restrict__ oat, const unsigned short* __restrict__ wot,
    float* __restrict__ out) {
  gemm_core<true, true>((const void*)oat, wot, (void*)out);
}

// ---------------------------------------------------------------- attention
// grid (32, 24). 4 waves x 16 q-rows. Causal tiles kt=0..qt always; future
// tiles only if some row's visible window was fully padded (m_i = -10000):
// for rows with m_i > -5000, future scores <= -9995 -> exp underflows to 0
// exactly and max is unchanged, so skipping is bit-exact.
__global__ __launch_bounds__(256) void attn_kernel(
    const unsigned short* __restrict__ qh, const unsigned short* __restrict__ kh,
    const unsigned short* __restrict__ vh, const int* __restrict__ attn_mask,
    const int* __restrict__ mask_future, unsigned short* __restrict__ o) {
  const int S = 2048, HD = 64, NH = 12;
  const int qt = blockIdx.x;
  const int bh = blockIdx.y;
  const int b = bh / NH, h = bh % NH;
  const int tid = threadIdx.x;
  const int wave = tid >> 6, lane = tid & 63;
  const int quad = lane >> 4, l16 = lane & 15;

  __shared__ __align__(16) unsigned short Ks[64 * 72];
  __shared__ __align__(16) unsigned short Vt[64 * 72];
  __shared__ __align__(16) unsigned short Ps[4][16 * 72];
  __shared__ int Ms[64];
  __shared__ int s_flag;

  const size_t head_off = (size_t)(b * NH + h) * S * HD;
  const unsigned short* Kb = kh + head_off;
  const unsigned short* Vb = vh + head_off;

  const int mf = mask_future[0];
  if (tid == 0) s_flag = 0;

  const int qrowA = qt * 64 + wave * 16 + l16;
  v8s aQ[2];
  {
    const unsigned short* qp = qh + head_off + (size_t)qrowA * HD + quad * 8;
    aQ[0] = *(const v8s*)(qp);
    aQ[1] = *(const v8s*)(qp + 32);
  }
  const int qbase = qt * 64 + wave * 16 + quad * 4;

  float m_i[4], l_i[4];
  v4f accO[4];
#pragma unroll
  for (int i = 0; i < 4; i++) { m_i[i] = -1e30f; l_i[i] = 0.f; }
#pragma unroll
  for (int dt = 0; dt < 4; dt++) accO[dt] = (v4f){0.f, 0.f, 0.f, 0.f};

  const int kt_causal = mf ? qt : (S / 64 - 1);  // last always-needed tile

  for (int phase = 0; phase < 2; phase++) {
    int kt_lo, kt_hi;
    if (phase == 0) { kt_lo = 0; kt_hi = kt_causal; }
    else {
      // fallback only if some row's visible window was fully padded
      bool need = (m_i[0] < -5000.f) || (m_i[1] < -5000.f) ||
                  (m_i[2] < -5000.f) || (m_i[3] < -5000.f);
      if (need) s_flag = 1;  // benign race (0->1)
      __syncthreads();
      if (!s_flag) break;
      kt_lo = kt_causal + 1; kt_hi = S / 64 - 1;
    }
    for (int kt = kt_lo; kt <= kt_hi; kt++) {
      __syncthreads();
      {
        const uint4* srck = (const uint4*)(Kb + (size_t)kt * 64 * HD);
        const uint4* srcv = (const uint4*)(Vb + (size_t)kt * 64 * HD);
#pragma unroll
        for (int p = 0; p < 2; p++) {
          int idx = p * 256 + tid;
          int r = idx >> 3;
          int c0 = (idx & 7) << 3;
          *(uint4*)&Ks[r * 72 + c0] = srck[idx];
          v8u vv;
          *(uint4*)&vv = srcv[idx];
          int shift = (idx & 7) << 3;
#pragma unroll
          for (int i = 0; i < 8; i++) {
            int d = c0 + i;
            int scol = (r + shift) & 63;  // diagonal swizzle
            Vt[d * 72 + scol] = vv[i];
          }
        }
        if (tid < 64) Ms[tid] = attn_mask[b * S + kt * 64 + tid];
      }
      __syncthreads();

      // S = Q K^T
      v4f sc[4];
#pragma unroll
      for (int nt = 0; nt < 4; nt++) {
        const unsigned short* kp = &Ks[(nt * 16 + l16) * 72 + quad * 8];
        v8s b0 = *(const v8s*)kp;
        v8s b1 = *(const v8s*)(kp + 32);
        v4f z = (v4f){0.f, 0.f, 0.f, 0.f};
        z = __builtin_amdgcn_mfma_f32_16x16x32_bf16(aQ[0], b0, z, 0, 0, 0);
        z = __builtin_amdgcn_mfma_f32_16x16x32_bf16(aQ[1], b1, z, 0, 0, 0);
        sc[nt] = z;
      }

      // scale + causal (additive) + padding (replace) — exact ref semantics
#pragma unroll
      for (int nt = 0; nt < 4; nt++) {
        int key = kt * 64 + nt * 16 + l16;
        bool pad = (Ms[nt * 16 + l16] == 0);
#pragma unroll
        for (int i = 0; i < 4; i++) {
          float v = sc[nt][i] * 0.125f;
          v += (mf && (key > qbase + i)) ? NEGV : 0.f;
          v = pad ? NEGV : v;
          sc[nt][i] = v;
        }
      }

      // online softmax
#pragma unroll
      for (int i = 0; i < 4; i++) {
        float mx = fmaxf(fmaxf(sc[0][i], sc[1][i]), fmaxf(sc[2][i], sc[3][i]));
        mx = fmaxf(mx, __shfl_xor(mx, 1));
        mx = fmaxf(mx, __shfl_xor(mx, 2));
        mx = fmaxf(mx, __shfl_xor(mx, 4));
        mx = fmaxf(mx, __shfl_xor(mx, 8));
        float mnew = fmaxf(m_i[i], mx);
        float alpha = __expf(m_i[i] - mnew);
        m_i[i] = mnew;
        float rs = 0.f;
#pragma unroll
        for (int nt = 0; nt < 4; nt++) {
          float p = __expf(sc[nt][i] - mnew);
          sc[nt][i] = p;
          rs += p;
        }
        rs += __shfl_xor(rs, 1);
        rs += __shfl_xor(rs, 2);
        rs += __shfl_xor(rs, 4);
        rs += __shfl_xor(rs, 8);
        l_i[i] = l_i[i] * alpha + rs;
#pragma unroll
        for (int dt = 0; dt < 4; dt++) accO[dt][i] *= alpha;
      }

      // P: C-layout regs -> per-wave LDS -> A-layout frags
#pragma unroll
      for (int nt = 0; nt < 4; nt++)
#pragma unroll
        for (int i = 0; i < 4; i++)
          Ps[wave][(quad * 4 + i) * 72 + nt * 16 + l16] = f2bf(sc[nt][i]);

#pragma unroll
      for (int ks = 0; ks < 2; ks++) {
        v8s aP = *(const v8s*)&Ps[wave][l16 * 72 + ks * 32 + quad * 8];
#pragma unroll
        for (int dt = 0; dt < 4; dt++) {
          int d = dt * 16 + l16;
          int scol = ((ks * 32 + quad * 8) + ((d >> 3) << 3)) & 63;
          v8s bV = *(const v8s*)&Vt[d * 72 + scol];
          accO[dt] =
              __builtin_amdgcn_mfma_f32_16x16x32_bf16(aP, bV, accO[dt], 0, 0, 0);
        }
      }
    }
    if (phase == 0) __syncthreads();  // all waves done before flag vote
  }

  // normalize + store O bf16 head-major over own Q region (in place)
#pragma unroll
  for (int i = 0; i < 4; i++) {
    float inv = 1.f / l_i[i];
    int qr = qbase + i;
    size_t base = head_off + (size_t)qr * HD;
#pragma unroll
    for (int dt = 0; dt < 4; dt++)
      o[base + dt * 16 + l16] = f2bf(accO[dt][i] * inv);
  }
}

// ---------------------------------------------------------------- launch
extern "C" void kernel_launch(void* const* d_in, const int* in_sizes, int n_in,
                              void* d_out, int out_size, void* d_ws, size_t ws_size,
                              hipStream_t stream) {
  const float* q  = (const float*)d_in[0];
  const float* k  = (const float*)d_in[1];
  const float* v  = (const float*)d_in[2];
  const int* amask = (const int*)d_in[3];
  const float* Wq = (const float*)d_in[4];
  const float* Wk = (const float*)d_in[5];
  const float* Wv = (const float*)d_in[6];
  const float* Wo = (const float*)d_in[7];
  const int* mf  = (const int*)d_in[8];
  float* out = (float*)d_out;

  unsigned short* ws = (unsigned short*)d_ws;
  unsigned short* qh = ws;                  // O overwrites qh after attention
  unsigned short* kh = qh + 3145728;
  unsigned short* vh = kh + 3145728;
  unsigned short* wqt = vh + 3145728;
  unsigned short* wkt = wqt + 589824;
  unsigned short* wvt = wkt + 589824;
  unsigned short* wot = wvt + 589824;

  transpose_w<<<dim3(24, 24, 4), 256, 0, stream>>>(Wq, Wk, Wv, Wo,
                                                   wqt, wkt, wvt, wot);
  gemm_qkv<<<dim3(32, 6, 3), 256, 0, stream>>>(q, k, v, wqt, wkt, wvt,
                                               qh, kh, vh);
  attn_kernel<<<dim3(32, 24), 256, 0, stream>>>(qh, kh, vh, amask, mf, qh);
  gemm_o<<<dim3(32, 6), 256, 0, stream>>>(qh, wot, out);
}